// Round 2
// baseline (281288.110 us; speedup 1.0000x reference)
//
#include <hip/hip_runtime.h>

// ---------------------------------------------------------------------------
// KAN-RNN on MI355X.
// Persistent kernel: 256 WGs = 32 row-groups (32 batch rows) x 8 col-slices
// (64 cols). Group = 8 WGs (one per XCD; slice = bid&7 so each XCD's L2 holds
// only its 1.2 MB weight slice for all 1024 steps). Per step: 2 layers, each
// = feature expansion (silu + 8 cubic B-spline bases per scalar, fp16) into
// XOR-swizzled LDS chunks + MFMA f32_16x16x32_f16 against fragment-linear
// pre-packed fp16 weights.
// R1 fix: cross-WG h/h1 exchange goes through L3 via RELAXED SYSTEM-scope
// atomics (UC, sc0 sc1) -> NO acquire/release cache maintenance -> weights
// stay L2-resident (R0 refetched 20 MB/step from HBM due to barrier's
// buffer_inv). Barrier: per-wave s_waitcnt vmcnt(0) + one relaxed system
// fetch_add + relaxed spin. h-values double-buffered in regs (next chunk's
// 8 UC loads issued before current build) to hide ~600cy L3 latency.
// Workspace: W1p 4.85MB | W2p 4.72MB | h f32 2MB | h1 f32 2MB | counters.
// ---------------------------------------------------------------------------

typedef _Float16 f16;
typedef _Float16 f16x8 __attribute__((ext_vector_type(8)));
typedef float    f32x4 __attribute__((ext_vector_type(4)));

#define K1S 148   // layer1 k-steps of 32: 128 (x-part, 108 used) + 8*576
#define K2S 144   // layer2: 8 chunks * 576 / 32
#define OFF_W1P 0
#define OFF_W2P 4849664      // 4736*512*2
#define OFF_H   9568256      // + 4608*512*2
#define OFF_H1  11665408     // + 1024*512*4
#define OFF_CNT 13762560     // + 1024*512*4

__device__ __forceinline__ float ucload(const float* p) {
  return __hip_atomic_load((float*)p, __ATOMIC_RELAXED, __HIP_MEMORY_SCOPE_SYSTEM);
}
__device__ __forceinline__ void ucstore(float* p, float v) {
  __hip_atomic_store(p, v, __ATOMIC_RELAXED, __HIP_MEMORY_SCOPE_SYSTEM);
}

// 9 features of scalar z: f[0]=silu(z); f[1+g]=B_g(z), g=0..7 (cubic B-spline,
// knots t_m = m*0.4 - 1, m=-3..8; support [-2.2, 2.2)).
__device__ __forceinline__ void feat9(float z, float f9[9]) {
  float s  = z / (1.f + __expf(-z));
  float q  = (z + 1.f) * 2.5f;
  float mf = floorf(q);
  float u  = q - mf;
  int   mi = (int)mf;
  if (!(mf >= -3.f && mf <= 7.f)) mi = 100;   // outside support -> all zero
  float u2 = u*u, u3 = u2*u, omu = 1.f - u;
  float p0 = omu*omu*omu * (1.f/6.f);
  float p1 = (3.f*u3 - 6.f*u2 + 4.f) * (1.f/6.f);
  float p2 = (-3.f*u3 + 3.f*u2 + 3.f*u + 1.f) * (1.f/6.f);
  float p3 = u3 * (1.f/6.f);
  f9[0] = s;
#pragma unroll
  for (int g = 0; g < 8; ++g) {
    int d = g - mi;            // 0..3 selects which of the 4 live polys
    float v = 0.f;
    v = (d==0) ? p0 : v; v = (d==1) ? p1 : v;
    v = (d==2) ? p2 : v; v = (d==3) ? p3 : v;
    f9[1+g] = v;
  }
}

// Pack weights fp32 -> fp16 in fragment-linear order:
// element index = ((nt*KS + ks)*64 + lane)*8 + e  holds W[k][n] with
// k = ks*32 + (lane>>4)*8 + e, n = nt*16 + (lane&15)   (MFMA B-frag layout).
__global__ void __launch_bounds__(256)
pack_w(const float* __restrict__ bw1, const float* __restrict__ sw1,
       const float* __restrict__ bw2, const float* __restrict__ sw2,
       f16* __restrict__ w1p, f16* __restrict__ w2p)
{
  long idx = (long)blockIdx.x * 256 + threadIdx.x;
  const long N1 = 2424832L;               // 4736*512
  if (idx < N1) {
    int e = (int)(idx & 7); long q = idx >> 3;
    int l = (int)(q & 63);  q >>= 6;
    int ks = (int)(q % K1S); int nt = (int)(q / K1S);
    int k = ks*32 + (l>>4)*8 + e;
    int n = nt*16 + (l & 15);
    float v = 0.f;
    if (k < 108) {
      int f = k / 12, i = k - f*12;
      v = (f == 0) ? bw1[n*524 + i] : sw1[((n*524 + i) << 3) + f - 1];
    } else if (k >= 128) {
      int kh = k - 128; int c = kh / 576; int w_ = kh - c*576;
      int f = w_ >> 6, sc = w_ & 63; int i = 12 + c*64 + sc;
      v = (f == 0) ? bw1[n*524 + i] : sw1[((n*524 + i) << 3) + f - 1];
    }
    w1p[idx] = (f16)v;
  } else {
    idx -= N1;                            // 0 .. 4608*512
    int e = (int)(idx & 7); long q = idx >> 3;
    int l = (int)(q & 63);  q >>= 6;
    int ks = (int)(q % K2S); int nt = (int)(q / K2S);
    int k = ks*32 + (l>>4)*8 + e;
    int n = nt*16 + (l & 15);
    int c = k / 576; int w_ = k - c*576;
    int f = w_ >> 6, sc = w_ & 63; int i = c*64 + sc;
    float v = (f == 0) ? bw2[n*512 + i] : sw2[((n*512 + i) << 3) + f - 1];
    w2p[idx] = (f16)v;
  }
}

// Group barrier with NO cache maintenance: every wave drains its UC stores
// (vmcnt(0)), then one relaxed system RMW + relaxed spin (both execute at L3,
// which is coherent across XCDs). No buffer_inv / buffer_wbl2 -> L2 weights
// survive.
__device__ __forceinline__ void grp_barrier(unsigned* cnt, unsigned target) {
  asm volatile("s_waitcnt vmcnt(0)" ::: "memory");
  __syncthreads();
  if (threadIdx.x == 0) {
    __hip_atomic_fetch_add(cnt, 1u, __ATOMIC_RELAXED, __HIP_MEMORY_SCOPE_SYSTEM);
    unsigned v;
    do {
      v = __hip_atomic_load(cnt, __ATOMIC_RELAXED, __HIP_MEMORY_SCOPE_SYSTEM);
      if (v < target) __builtin_amdgcn_s_sleep(1);
    } while (v < target);
  }
  __syncthreads();
  __atomic_signal_fence(__ATOMIC_SEQ_CST);
}

#define LOADH(SRC, DST, c)                                                  \
  _Pragma("unroll") for (int j = 0; j < 8; ++j)                             \
    DST[j] = ucload((SRC) + (c)*64 + ibB*8 + j);

#define BUILD(CUR) {                                                        \
  f16 o[9][8];                                                              \
  _Pragma("unroll") for (int j = 0; j < 8; ++j) {                           \
    float f9[9]; feat9(CUR[j], f9);                                         \
    _Pragma("unroll") for (int f = 0; f < 9; ++f) o[f][j] = (f16)f9[f]; }   \
  _Pragma("unroll") for (int f = 0; f < 9; ++f) {                           \
    f16x8 v;                                                                \
    _Pragma("unroll") for (int e = 0; e < 8; ++e) v[e] = o[f][e];           \
    *(f16x8*)(feat + rbaseB + ((f*128 + ibB*16) ^ swB)) = v; } }

#define MFMA18(W, bA_, bB_, KSG) {                                          \
  _Pragma("unroll") for (int ks = 0; ks < 18; ++ks) {                       \
    f16x8 a = *(const f16x8*)(feat + abase + ((ks*64 + lHi16) ^ asw));      \
    f16x8 b0 = (W)[(bA_) + ((KSG) + ks)*64];                                \
    f16x8 b1 = (W)[(bB_) + ((KSG) + ks)*64];                                \
    acc0 = __builtin_amdgcn_mfma_f32_16x16x32_f16(a, b0, acc0, 0, 0, 0);    \
    acc1 = __builtin_amdgcn_mfma_f32_16x16x32_f16(a, b1, acc1, 0, 0, 0); } }

// chunk c: issue next chunk's h loads (hide L3 latency under build+MFMA),
// sync (prev chunk's readers done), build features into LDS, sync, MFMA.
#define CHUNK(c, CUR, NXT, SRC, W, bA_, bB_, KSGBASE)                       \
  { if ((c) < 7) { LOADH(SRC, NXT, (c)+1) }                                 \
    __syncthreads(); BUILD(CUR) __syncthreads();                            \
    MFMA18(W, bA_, bB_, (KSGBASE) + (c)*18) }

__global__ void __launch_bounds__(256)
kan_rnn(const float* __restrict__ xseq, const f16* __restrict__ w1p,
        const f16* __restrict__ w2p, float* __restrict__ hbuf,
        float* __restrict__ h1buf, unsigned* __restrict__ counters)
{
  // LDS: feature chunk [32 rows][576 k] fp16 (XOR-swizzled) + x-part [32][128]
  __shared__ __align__(16) unsigned char feat [32 * 1152];   // 36 KB
  __shared__ __align__(16) unsigned char xfeat[32 * 256];    // 8 KB

  const int tid = threadIdx.x, bid = blockIdx.x;
  const int slice = bid & 7, grp = bid >> 3, r0 = grp * 32;
  const int wv = tid >> 6, l = tid & 63;
  const int mt = wv & 1, ntp = wv >> 1;         // Mtile, Ntile-pair
  const int lLo = l & 15, lHi16 = (l >> 4) * 16;
  // feature-build role: thread -> (row rB, 8 scalars at ibB*8)
  const int rB = tid >> 3, ibB = tid & 7;
  const int swB = (rB & 7) << 4, rbaseB = rB * 1152;
  // A-fragment role
  const int ar = mt*16 + lLo;
  const int asw = (ar & 7) << 4;
  const int abase = ar * 1152, axbase = ar * 256;
  const int n0 = slice*4 + ntp*2;               // global 16-col tile index
  unsigned* cnt = counters + grp;

  // zero x-feature pad (k = 108..127, all rows) once
  for (int idx = tid; idx < 32*20; idx += 256) {
    int r = idx / 20, k = 108 + (idx % 20);
    *(f16*)(xfeat + r*256 + ((k*2) ^ ((r & 7) << 4))) = (f16)0.f;
  }

  const float* srcRow1 = hbuf  + (size_t)(r0 + rB) * 512;
  const float* srcRow2 = h1buf + (size_t)(r0 + rB) * 512;
  float* dstH1 = h1buf;
  const f16x8* W1 = (const f16x8*)w1p;
  const f16x8* W2 = (const f16x8*)w2p;
  const int bL1a = (n0*K1S)*64 + l, bL1b = ((n0+1)*K1S)*64 + l;
  const int bL2a = (n0*K2S)*64 + l, bL2b = ((n0+1)*K2S)*64 + l;

  float bufA[8], bufB[8];
  unsigned target = 0;
  for (int t = 0; t < 1024; ++t) {
    // ================= layer 1 =================
    LOADH(srcRow1, bufA, 0)                       // chunk-0 h, in flight
    // x features (h-independent part of z = [x_t, h])
    for (int idx = tid; idx < 384; idx += 256) {
      int r = idx / 12, i = idx - r*12;
      float z = xseq[(size_t)(r0 + r)*12288 + t*12 + i];
      float f9[9]; feat9(z, f9);
#pragma unroll
      for (int f = 0; f < 9; ++f)
        *(f16*)(xfeat + r*256 + (((f*12 + i)*2) ^ ((r & 7) << 4))) = (f16)f9[f];
    }
    f32x4 acc0 = {0.f,0.f,0.f,0.f}, acc1 = {0.f,0.f,0.f,0.f};
    __syncthreads();
    // x-chunk MFMA (4 k-steps)
#pragma unroll
    for (int ks = 0; ks < 4; ++ks) {
      f16x8 a = *(const f16x8*)(xfeat + axbase + ((ks*64 + lHi16) ^ asw));
      f16x8 b0 = W1[bL1a + ks*64];
      f16x8 b1 = W1[bL1b + ks*64];
      acc0 = __builtin_amdgcn_mfma_f32_16x16x32_f16(a, b0, acc0, 0, 0, 0);
      acc1 = __builtin_amdgcn_mfma_f32_16x16x32_f16(a, b1, acc1, 0, 0, 0);
    }
    // 8 h-chunks of 64 scalars (K=576 each)
    CHUNK(0, bufA, bufB, srcRow1, W1, bL1a, bL1b, 4)
    CHUNK(1, bufB, bufA, srcRow1, W1, bL1a, bL1b, 4)
    CHUNK(2, bufA, bufB, srcRow1, W1, bL1a, bL1b, 4)
    CHUNK(3, bufB, bufA, srcRow1, W1, bL1a, bL1b, 4)
    CHUNK(4, bufA, bufB, srcRow1, W1, bL1a, bL1b, 4)
    CHUNK(5, bufB, bufA, srcRow1, W1, bL1a, bL1b, 4)
    CHUNK(6, bufA, bufB, srcRow1, W1, bL1a, bL1b, 4)
    CHUNK(7, bufB, bufA, srcRow1, W1, bL1a, bL1b, 4)
    // store h1 slice (UC f32): D layout col=l&15, row=(l>>4)*4+reg
#pragma unroll
    for (int reg = 0; reg < 4; ++reg) {
      int gr = r0 + mt*16 + (l >> 4)*4 + reg;
      ucstore(dstH1 + (size_t)gr*512 + (n0*16     + lLo), acc0[reg]);
      ucstore(dstH1 + (size_t)gr*512 + ((n0+1)*16 + lLo), acc1[reg]);
    }
    target += 8; grp_barrier(cnt, target);

    // ================= layer 2 =================
    LOADH(srcRow2, bufA, 0)
    acc0 = (f32x4){0.f,0.f,0.f,0.f}; acc1 = (f32x4){0.f,0.f,0.f,0.f};
    CHUNK(0, bufA, bufB, srcRow2, W2, bL2a, bL2b, 0)
    CHUNK(1, bufB, bufA, srcRow2, W2, bL2a, bL2b, 0)
    CHUNK(2, bufA, bufB, srcRow2, W2, bL2a, bL2b, 0)
    CHUNK(3, bufB, bufA, srcRow2, W2, bL2a, bL2b, 0)
    CHUNK(4, bufA, bufB, srcRow2, W2, bL2a, bL2b, 0)
    CHUNK(5, bufB, bufA, srcRow2, W2, bL2a, bL2b, 0)
    CHUNK(6, bufA, bufB, srcRow2, W2, bL2a, bL2b, 0)
    CHUNK(7, bufB, bufA, srcRow2, W2, bL2a, bL2b, 0)
    // h_new = tanh(.) stored UC f32
#pragma unroll
    for (int reg = 0; reg < 4; ++reg) {
      int gr = r0 + mt*16 + (l >> 4)*4 + reg;
      float v0 = acc0[reg]; v0 = 1.f - 2.f / (__expf(2.f*v0) + 1.f);
      float v1 = acc1[reg]; v1 = 1.f - 2.f / (__expf(2.f*v1) + 1.f);
      ucstore(hbuf + (size_t)gr*512 + (n0*16     + lLo), v0);
      ucstore(hbuf + (size_t)gr*512 + ((n0+1)*16 + lLo), v1);
    }
    target += 8; grp_barrier(cnt, target);
  }
}

__global__ void __launch_bounds__(64)
out_k(const float* __restrict__ hbuf, const float* __restrict__ wout,
      const float* __restrict__ bout, float* __restrict__ out)
{
  int b = blockIdx.x, l = threadIdx.x;
  float s0 = 0.f, s1 = 0.f, s2 = 0.f;
  for (int j = l; j < 512; j += 64) {
    float hv = hbuf[(size_t)b*512 + j];
    s0 += hv * wout[j]; s1 += hv * wout[512 + j]; s2 += hv * wout[1024 + j];
  }
#pragma unroll
  for (int off = 32; off > 0; off >>= 1) {
    s0 += __shfl_down(s0, off);
    s1 += __shfl_down(s1, off);
    s2 += __shfl_down(s2, off);
  }
  if (l == 0) {
    out[b*3 + 0] = s0 + bout[0];
    out[b*3 + 1] = s1 + bout[1];
    out[b*3 + 2] = s2 + bout[2];
  }
}

extern "C" void kernel_launch(void* const* d_in, const int* in_sizes, int n_in,
                              void* d_out, int out_size, void* d_ws, size_t ws_size,
                              hipStream_t stream) {
  const float* xseq = (const float*)d_in[0];
  const float* bw1  = (const float*)d_in[1];
  const float* sw1  = (const float*)d_in[2];
  const float* bw2  = (const float*)d_in[3];
  const float* sw2  = (const float*)d_in[4];
  const float* wout = (const float*)d_in[5];
  const float* bout = (const float*)d_in[6];
  char* ws = (char*)d_ws;
  f16*      w1p  = (f16*)(ws + OFF_W1P);
  f16*      w2p  = (f16*)(ws + OFF_W2P);
  float*    hbuf = (float*)(ws + OFF_H);
  float*    h1b  = (float*)(ws + OFF_H1);
  unsigned* cnts = (unsigned*)(ws + OFF_CNT);

  hipMemsetAsync(hbuf, 0, 1024*512*4, stream);   // h0 = 0
  hipMemsetAsync(cnts, 0, 128, stream);          // barrier counters
  pack_w<<<18688, 256, 0, stream>>>(bw1, sw1, bw2, sw2, w1p, w2p);
  kan_rnn<<<256, 256, 0, stream>>>(xseq, w1p, w2p, hbuf, h1b, cnts);
  out_k<<<1024, 64, 0, stream>>>(hbuf, wout, bout, (float*)d_out);
}

// Round 4
// 63996.899 us; speedup vs baseline: 4.3953x; 4.3953x over previous
//
#include <hip/hip_runtime.h>

// ---------------------------------------------------------------------------
// KAN-RNN on MI355X.  256 persistent WGs = 32 row-groups (32 rows) x 8
// col-slices (64 cols, slice = bid&7 -> XCD-pinned L2-resident weights).
// Cross-WG h/h1 exchange via SYSTEM-relaxed atomics (no cache maintenance ->
// weights never invalidated) in a PACKED layout defined by the consumer's
// load order: each wave load instruction covers a contiguous 512B span of L3
// (zero fetch amplification; R1's scalar UC loads amplified 8x -> 203GB).
// Per step: 2 layers; per layer 8 chunks of 64 h-scalars -> 9 features each
// (silu + 8 cubic B-spline bases, fp16) into double-buffered XOR-swizzled
// LDS; MFMA f32_16x16x32_f16 vs fragment-linear fp16 weights; one
// __syncthreads per chunk with MFMA(c) || BUILD(c+1) between barriers.
// B-spline select: p0..p3 packed f16x4 in 64b -> v_lshrrev_b64 by 16(g-mi).
// R3: fix cvt_pkrtz return-type mismatch (bit_cast via auto).
// ---------------------------------------------------------------------------

typedef _Float16 f16;
typedef _Float16 f16x8 __attribute__((ext_vector_type(8)));
typedef float    f32x4 __attribute__((ext_vector_type(4)));
typedef unsigned long long u64;
typedef unsigned int u32;
typedef u32 u32x4 __attribute__((ext_vector_type(4)));

#define K1S 148   // layer1 k-steps of 32: 128 (x-part, 108 used) + 8*576
#define K2S 144   // layer2: 8 chunks * 576 / 32
#define OFF_W1P 0
#define OFF_W2P 4849664      // 4736*512*2
#define OFF_H   9568256      // + 4608*512*2
#define OFF_H1  11665408     // + 1024*512*4
#define OFF_CNT 13762560     // + 1024*512*4

__device__ __forceinline__ u64 ucload64(const u64* p){
  return __hip_atomic_load((u64*)p, __ATOMIC_RELAXED, __HIP_MEMORY_SCOPE_SYSTEM);
}
__device__ __forceinline__ void ucstoref(float* p, float v){
  __hip_atomic_store(p, v, __ATOMIC_RELAXED, __HIP_MEMORY_SCOPE_SYSTEM);
}
__device__ __forceinline__ u32 pk2(float a, float b){
  auto v = __builtin_amdgcn_cvt_pkrtz(a, b);   // __fp16 ext_vector(2)
  return __builtin_bit_cast(u32, v);
}

// Per-scalar spline state: P = {p0,p1,p2,p3} as 4 f16 in 64b; msh = 16*mi.
struct SplS { u64 P; int msh; float silu; };
__device__ __forceinline__ SplS spl(float z){
  SplS r;
  r.silu = z / (1.f + __expf(-z));
  float q  = fmaf(z, 2.5f, 2.5f);
  float mf = floorf(q);
  float u  = q - mf;
  int mi = (int)mf;
  mi = (mf >= -3.f && mf <= 7.f) ? mi : 100;   // out of support -> all zero
  float u2=u*u, u3=u2*u, om=1.f-u;
  float p0 = om*om*om*(1.f/6.f);
  float p1 = fmaf(u3, 0.5f, fmaf(u2,-1.f, (2.f/3.f)));
  float p2 = fmaf(u3,-0.5f, fmaf(u2, 0.5f, fmaf(u,0.5f,(1.f/6.f))));
  float p3 = u3*(1.f/6.f);
  r.P   = ((u64)pk2(p2,p3) << 32) | pk2(p0,p1);
  r.msh = mi << 4;
  return r;
}
// basis g (f16 bits in low 16): halfword (g-mi) of P, 0 if g-mi not in [0,3]
__device__ __forceinline__ u32 bs1(const SplS& s, int g16){
  int sh = g16 - s.msh;
  u32 v = (u32)(s.P >> (sh & 63)) & 0xffffu;
  return ((u32)sh < 64u) ? v : 0u;
}

// Pack weights fp32 -> fp16, fragment-linear (unchanged from R0, verified):
// elem ((nt*KS+ks)*64+lane)*8+e = W[k][n], k=ks*32+(lane>>4)*8+e, n=nt*16+(lane&15)
__global__ void __launch_bounds__(256)
pack_w(const float* __restrict__ bw1, const float* __restrict__ sw1,
       const float* __restrict__ bw2, const float* __restrict__ sw2,
       f16* __restrict__ w1p, f16* __restrict__ w2p)
{
  long idx = (long)blockIdx.x * 256 + threadIdx.x;
  const long N1 = 2424832L;               // 4736*512
  if (idx < N1) {
    int e = (int)(idx & 7); long q = idx >> 3;
    int l = (int)(q & 63);  q >>= 6;
    int ks = (int)(q % K1S); int nt = (int)(q / K1S);
    int k = ks*32 + (l>>4)*8 + e;
    int n = nt*16 + (l & 15);
    float v = 0.f;
    if (k < 108) {
      int f = k / 12, i = k - f*12;
      v = (f == 0) ? bw1[n*524 + i] : sw1[((n*524 + i) << 3) + f - 1];
    } else if (k >= 128) {
      int kh = k - 128; int c = kh / 576; int w_ = kh - c*576;
      int f = w_ >> 6, sc = w_ & 63; int i = 12 + c*64 + sc;
      v = (f == 0) ? bw1[n*524 + i] : sw1[((n*524 + i) << 3) + f - 1];
    }
    w1p[idx] = (f16)v;
  } else {
    idx -= N1;
    int e = (int)(idx & 7); long q = idx >> 3;
    int l = (int)(q & 63);  q >>= 6;
    int ks = (int)(q % K2S); int nt = (int)(q / K2S);
    int k = ks*32 + (l>>4)*8 + e;
    int n = nt*16 + (l & 15);
    int c = k / 576; int w_ = k - c*576;
    int f = w_ >> 6, sc = w_ & 63; int i = c*64 + sc;
    float v = (f == 0) ? bw2[n*512 + i] : sw2[((n*512 + i) << 3) + f - 1];
    w2p[idx] = (f16)v;
  }
}

// Group barrier, zero cache maintenance (all RELAXED): drain UC stores,
// system-relaxed RMW at L3, relaxed spin.
__device__ __forceinline__ void grp_barrier(unsigned* cnt, unsigned target) {
  asm volatile("s_waitcnt vmcnt(0)" ::: "memory");
  __syncthreads();
  if (threadIdx.x == 0) {
    __hip_atomic_fetch_add(cnt, 1u, __ATOMIC_RELAXED, __HIP_MEMORY_SCOPE_SYSTEM);
    unsigned v;
    do {
      v = __hip_atomic_load(cnt, __ATOMIC_RELAXED, __HIP_MEMORY_SCOPE_SYSTEM);
      if (v < target) __builtin_amdgcn_s_sleep(1);
    } while (v < target);
  }
  __syncthreads();
  __builtin_amdgcn_sched_barrier(0);
}

// 4x 8B UC loads, wave-contiguous (512B/instruction at L3)
#define LOADH(SRCU, c, D)                                                  \
  { const u64* _p = (SRCU) + (c)*1024 + wv*64 + l;                         \
    D[0] = ucload64(_p);       D[1] = ucload64(_p + 256);                  \
    D[2] = ucload64(_p + 512); D[3] = ucload64(_p + 768); }

// 64 scalars -> 9 features -> swizzled LDS chunk (b128 writes)
#define BUILD(D, FB) {                                                     \
  u32 wrd[9][4];                                                           \
  _Pragma("unroll") for (int j = 0; j < 4; ++j) {                          \
    float z0 = __uint_as_float((u32)D[j]);                                 \
    float z1 = __uint_as_float((u32)(D[j] >> 32));                         \
    SplS s0 = spl(z0), s1 = spl(z1);                                       \
    f16 ha = (f16)s0.silu, hb_ = (f16)s1.silu;                             \
    wrd[0][j] = (u32)__builtin_bit_cast(unsigned short, ha)                \
              | ((u32)__builtin_bit_cast(unsigned short, hb_) << 16);      \
    _Pragma("unroll") for (int g = 0; g < 8; ++g)                          \
      wrd[1+g][j] = bs1(s0, g*16) | (bs1(s1, g*16) << 16);                 \
  }                                                                        \
  _Pragma("unroll") for (int f = 0; f < 9; ++f) {                          \
    u32x4 v = {wrd[f][0], wrd[f][1], wrd[f][2], wrd[f][3]};                \
    *(u32x4*)((FB) + rbaseB + ((f*128 + ibB*16) ^ swB)) = v;               \
  } }

#define MFMA18(FB, W, bA_, bB_, KSG) {                                     \
  _Pragma("unroll") for (int ks = 0; ks < 18; ++ks) {                      \
    f16x8 a  = *(const f16x8*)((FB) + abase + ((ks*64 + lHi16) ^ asw));    \
    f16x8 b0 = (W)[(bA_) + ((KSG) + ks)*64];                               \
    f16x8 b1 = (W)[(bB_) + ((KSG) + ks)*64];                               \
    acc0 = __builtin_amdgcn_mfma_f32_16x16x32_f16(a, b0, acc0, 0, 0, 0);   \
    acc1 = __builtin_amdgcn_mfma_f32_16x16x32_f16(a, b1, acc1, 0, 0, 0); } }

// x features for step T into xfeat (k = f*12 + i)
#define XBUILD(T)                                                          \
  for (int idx = tid; idx < 384; idx += 256) {                             \
    int r = idx / 12, i = idx - r*12;                                      \
    float z = xseq[(size_t)(r0 + r)*12288 + (T)*12 + i];                   \
    SplS s = spl(z);                                                       \
    int xb = r*256, sw = (r & 7) << 4;                                     \
    f16 hs = (f16)s.silu;                                                  \
    *(unsigned short*)(xfeat + xb + ((i*2) ^ sw)) =                        \
        __builtin_bit_cast(unsigned short, hs);                            \
    _Pragma("unroll") for (int g = 0; g < 8; ++g)                          \
      *(unsigned short*)(xfeat + xb + ((((1+g)*12 + i)*2) ^ sw)) =         \
        (unsigned short)bs1(s, g*16);                                      \
  }

__global__ void __launch_bounds__(256, 1)
kan_rnn(const float* __restrict__ xseq, const f16* __restrict__ w1p,
        const f16* __restrict__ w2p, float* __restrict__ hbuf,
        float* __restrict__ h1buf, unsigned* __restrict__ counters)
{
  __shared__ __align__(16) unsigned char feat[2][32*1152];   // 2 x 36 KB
  __shared__ __align__(16) unsigned char xfeat[32*256];      // 8 KB

  const int tid = threadIdx.x, bid = blockIdx.x;
  const int slice = bid & 7, grp = bid >> 3, r0 = grp * 32;
  const int wv = tid >> 6, l = tid & 63;
  const int mt = wv & 1, ntp = wv >> 1;
  const int lLo = l & 15, lHi16 = (l >> 4) * 16;
  // builder role: row rB = wv*8 + (l>>3), 8 scalars at ibB*8
  const int ibB = l & 7;
  const int rB = wv*8 + (l >> 3);
  const int swB = (l >> 3) << 4, rbaseB = rB * 1152;
  // MFMA A role
  const int ar = mt*16 + lLo;
  const int asw = (ar & 7) << 4;
  const int abase = ar * 1152, axbase = ar * 256;
  const int n0 = slice*4 + ntp*2;
  unsigned* cnt = counters + grp;

  // zero x-feature pad (k = 108..127)
  for (int idx = tid; idx < 32*20; idx += 256) {
    int r = idx / 20, k = 108 + (idx % 20);
    *(unsigned short*)(xfeat + r*256 + ((k*2) ^ ((r & 7) << 4))) = 0;
  }

  const u64* src1 = (const u64*)hbuf  + grp*8192;
  const u64* src2 = (const u64*)h1buf + grp*8192;
  const f16x8* W1 = (const f16x8*)w1p;
  const f16x8* W2 = (const f16x8*)w2p;
  const int bL1a = (n0*K1S)*64 + l, bL1b = ((n0+1)*K1S)*64 + l;
  const int bL2a = (n0*K2S)*64 + l, bL2b = ((n0+1)*K2S)*64 + l;

  // packed store offsets (f32 units), same layout for h and h1:
  // addr(row,k) = grp*16384 + (k>>6)*2048 + ((k>>1)&3)*512 + ((row>>3)&3)*128
  //             + (row&7)*16 + ((k>>3)&7)*2 + (k&1)
  int ofs[8];
  {
    int k0 = n0*16 + lLo, k1 = k0 + 16;
    int ko0 = (k0>>6)*2048 + ((k0>>1)&3)*512 + ((k0>>3)&7)*2 + (k0&1);
    int ko1 = (k1>>6)*2048 + ((k1>>1)&3)*512 + ((k1>>3)&7)*2 + (k1&1);
#pragma unroll
    for (int reg = 0; reg < 4; ++reg) {
      int row = mt*16 + (l >> 4)*4 + reg;
      int ro = ((row>>3)&3)*128 + (row&7)*16;
      ofs[reg]   = grp*16384 + ko0 + ro;
      ofs[4+reg] = grp*16384 + ko1 + ro;
    }
  }

  XBUILD(0)
  __syncthreads();

  u64 hA[4], hB[4];
  unsigned target = 0;
#pragma unroll 1
  for (int t = 0; t < 1024; ++t) {
    // ---------------- layer 1 ----------------
    LOADH(src1, 0, hA)
    f32x4 acc0 = {0.f,0.f,0.f,0.f}, acc1 = {0.f,0.f,0.f,0.f};
    // x-part MFMA (4 ksteps) while chunk0 h loads fly
#pragma unroll
    for (int ks = 0; ks < 4; ++ks) {
      f16x8 a  = *(const f16x8*)(xfeat + axbase + ((ks*64 + lHi16) ^ asw));
      f16x8 b0 = W1[bL1a + ks*64];
      f16x8 b1 = W1[bL1b + ks*64];
      acc0 = __builtin_amdgcn_mfma_f32_16x16x32_f16(a, b0, acc0, 0, 0, 0);
      acc1 = __builtin_amdgcn_mfma_f32_16x16x32_f16(a, b1, acc1, 0, 0, 0);
    }
    BUILD(hA, feat[0])
#pragma unroll 1
    for (int c2 = 0; c2 < 4; ++c2) {
      int ce = 2*c2;
      LOADH(src1, ce+1, hB)
      __syncthreads();
      MFMA18(feat[0], W1, bL1a, bL1b, 4 + ce*18)
      BUILD(hB, feat[1])
      if (c2 < 3) LOADH(src1, ce+2, hA)
      __syncthreads();
      MFMA18(feat[1], W1, bL1a, bL1b, 4 + (ce+1)*18)
      if (c2 < 3) BUILD(hA, feat[0])
    }
#pragma unroll
    for (int reg = 0; reg < 4; ++reg) {
      ucstoref(h1buf + ofs[reg],   acc0[reg]);
      ucstoref(h1buf + ofs[4+reg], acc1[reg]);
    }
    target += 8; grp_barrier(cnt, target);

    // ---------------- layer 2 ----------------
    LOADH(src2, 0, hA)
    acc0 = (f32x4){0.f,0.f,0.f,0.f}; acc1 = (f32x4){0.f,0.f,0.f,0.f};
    BUILD(hA, feat[0])
#pragma unroll 1
    for (int c2 = 0; c2 < 4; ++c2) {
      int ce = 2*c2;
      LOADH(src2, ce+1, hB)
      __syncthreads();
      MFMA18(feat[0], W2, bL2a, bL2b, ce*18)
      BUILD(hB, feat[1])
      if (c2 < 3) LOADH(src2, ce+2, hA)
      __syncthreads();
      MFMA18(feat[1], W2, bL2a, bL2b, (ce+1)*18)
      if (c2 < 3) BUILD(hA, feat[0])
    }
    // h_new = tanh(.), UC store packed
#pragma unroll
    for (int reg = 0; reg < 4; ++reg) {
      float v0 = acc0[reg]; v0 = 1.f - 2.f / (__expf(2.f*v0) + 1.f);
      float v1 = acc1[reg]; v1 = 1.f - 2.f / (__expf(2.f*v1) + 1.f);
      ucstoref(hbuf + ofs[reg],   v0);
      ucstoref(hbuf + ofs[4+reg], v1);
    }
    // next step's x features (hides barrier latency)
    if (t < 1023) { XBUILD(t+1) }
    target += 8; grp_barrier(cnt, target);
  }
}

__global__ void __launch_bounds__(64)
out_k(const float* __restrict__ hbuf, const float* __restrict__ wout,
      const float* __restrict__ bout, float* __restrict__ out)
{
  int b = blockIdx.x, l = threadIdx.x;
  int c = l >> 3, ib = l & 7;
  const float* hb = hbuf + (b>>5)*16384 + c*2048 + ((b>>3)&3)*128
                  + (b&7)*16 + ib*2;
  float s0 = 0.f, s1 = 0.f, s2 = 0.f;
#pragma unroll
  for (int j = 0; j < 4; ++j) {
    float2 v = *(const float2*)(hb + j*512);
    int k = c*64 + ib*8 + 2*j;
    s0 += v.x*wout[k]        + v.y*wout[k+1];
    s1 += v.x*wout[512 + k]  + v.y*wout[512 + k+1];
    s2 += v.x*wout[1024 + k] + v.y*wout[1024 + k+1];
  }
#pragma unroll
  for (int off = 32; off > 0; off >>= 1) {
    s0 += __shfl_down(s0, off);
    s1 += __shfl_down(s1, off);
    s2 += __shfl_down(s2, off);
  }
  if (l == 0) {
    out[b*3 + 0] = s0 + bout[0];
    out[b*3 + 1] = s1 + bout[1];
    out[b*3 + 2] = s2 + bout[2];
  }
}

extern "C" void kernel_launch(void* const* d_in, const int* in_sizes, int n_in,
                              void* d_out, int out_size, void* d_ws, size_t ws_size,
                              hipStream_t stream) {
  const float* xseq = (const float*)d_in[0];
  const float* bw1  = (const float*)d_in[1];
  const float* sw1  = (const float*)d_in[2];
  const float* bw2  = (const float*)d_in[3];
  const float* sw2  = (const float*)d_in[4];
  const float* wout = (const float*)d_in[5];
  const float* bout = (const float*)d_in[6];
  char* ws = (char*)d_ws;
  f16*      w1p  = (f16*)(ws + OFF_W1P);
  f16*      w2p  = (f16*)(ws + OFF_W2P);
  float*    hbuf = (float*)(ws + OFF_H);
  float*    h1b  = (float*)(ws + OFF_H1);
  unsigned* cnts = (unsigned*)(ws + OFF_CNT);

  hipMemsetAsync(hbuf, 0, 1024*512*4, stream);   // h0 = 0 (packed zeros)
  hipMemsetAsync(cnts, 0, 128, stream);          // barrier counters
  pack_w<<<18688, 256, 0, stream>>>(bw1, sw1, bw2, sw2, w1p, w2p);
  kan_rnn<<<256, 256, 0, stream>>>(xseq, w1p, w2p, hbuf, h1b, cnts);
  out_k<<<1024, 64, 0, stream>>>(hbuf, wout, bout, (float*)d_out);
}